// Round 7
// baseline (323.025 us; speedup 1.0000x reference)
//
#include <hip/hip_runtime.h>

typedef __bf16 bf16_t;
typedef __bf16 bf16x8 __attribute__((ext_vector_type(8)));
typedef float f32x4 __attribute__((ext_vector_type(4)));

#define MFMA_16x16x32(a, b, c) __builtin_amdgcn_mfma_f32_16x16x32_bf16((a), (b), (c), 0, 0, 0)
#define LOG2E 1.4426950408889634f

__device__ inline bf16x8 cvt8(const float* __restrict__ p) {
  bf16x8 r;
#pragma unroll
  for (int j = 0; j < 8; j++) r[j] = (bf16_t)p[j];
  return r;
}

// async 16B global->LDS DMA: LDS dest = (wave-uniform) base + lane*16B
__device__ inline void load_lds16(const bf16_t* g, bf16_t* l) {
  __builtin_amdgcn_global_load_lds(
      (const __attribute__((address_space(1))) void*)g,
      (__attribute__((address_space(3))) void*)l, 16, 0, 0);
}

// ---------------------------------------------------------------------------
// prep_k: fused convert (fp32->bf16 for x, qkv_w, proj_w) + bias gather.
// Fusion removes one kernel-launch gap. bias is pre-scaled by log2e so attn
// can use v_exp_f32 (2^x) directly.
// bias layout (TRANSPOSED fragment-major for swapped QK^T):
//   biasws[h*65536 + qb*4096 + ct*256 + L*4 + r]
//     = log2e * bias[h][q = qb*16 + (L&15)][k = ct*16 + (L>>4)*4 + r]
// ---------------------------------------------------------------------------
__global__ __launch_bounds__(256) void prep_k(
    const float* __restrict__ x, const float* __restrict__ qkv_w,
    const float* __restrict__ proj_w, const float* __restrict__ table,
    const int* __restrict__ rel,
    bf16_t* __restrict__ xbf, bf16_t* __restrict__ wqkvbf,
    bf16_t* __restrict__ wprojbf, float* __restrict__ biasws) {
  const int bid = blockIdx.x;
  if (bid < 8704) {
    size_t base = ((size_t)bid * 256 + threadIdx.x) * 8;
    if (base < 16777216) {
      *(bf16x8*)(xbf + base) = cvt8(x + base);
    } else if (base < 17563648) {
      size_t o = base - 16777216;
      *(bf16x8*)(wqkvbf + o) = cvt8(qkv_w + o);
    } else {
      size_t o = base - 17563648;
      *(bf16x8*)(wprojbf + o) = cvt8(proj_w + o);
    }
  } else {
    int idx = (bid - 8704) * 256 + threadIdx.x;  // 0 .. 1048576
    int h = idx >> 16;
    int rem = idx & 65535;
    int qb = rem >> 12;
    int ct = (rem >> 8) & 15;
    int L = (rem >> 2) & 63;
    int r = idx & 3;
    int q = qb * 16 + (L & 15);
    int k = ct * 16 + (L >> 4) * 4 + r;
    biasws[idx] = table[rel[q * 256 + k] * 16 + h] * LOG2E;
  }
}

// ---------------------------------------------------------------------------
// 128x128-tile 4-phase GEMM core, drain-at-phase-end schedule (r5 structure,
// halved geometry). 4 waves (2M x 2N), per-wave 64x64 output = acc[4][4].
// LDS 64 KiB (A,B 16KB K-tiles double-buffered, BK=64) -> 2 blocks/CU:
// two independent barrier groups per CU so one block's MFMA covers the
// other's gate/drain/restart stalls (the r5 1-block/CU lockstep cost).
// XOR swizzle slot^=row&7 on pre-swizzled global source + ds_read address.
// Counted vmcnt(4) gates; vmcnt(0) only at tail. Ledger identical to r5.
// ---------------------------------------------------------------------------
#define PH_OPEN() __builtin_amdgcn_s_setprio(1)

#define PH_CLOSE()                                        \
  do {                                                    \
    __builtin_amdgcn_s_setprio(0);                        \
    asm volatile("s_waitcnt lgkmcnt(0)" ::: "memory");    \
    __builtin_amdgcn_sched_barrier(0);                    \
    __builtin_amdgcn_s_barrier();                         \
    __builtin_amdgcn_sched_barrier(0);                    \
  } while (0)

#define GATE4()                                           \
  do {                                                    \
    __builtin_amdgcn_s_setprio(0);                        \
    asm volatile("s_waitcnt vmcnt(4)" ::: "memory");      \
    __builtin_amdgcn_s_barrier();                         \
    __builtin_amdgcn_sched_barrier(0);                    \
  } while (0)

#define GATE0()                                           \
  do {                                                    \
    __builtin_amdgcn_s_setprio(0);                        \
    asm volatile("s_waitcnt vmcnt(0)" ::: "memory");      \
    __builtin_amdgcn_s_barrier();                         \
    __builtin_amdgcn_sched_barrier(0);                    \
  } while (0)

// stage rows [c*32, c*32+64) of one 128x64 K-tile (256 thr: 32 rows/load)
#define STG2(src, dst, c)                                                        \
  do {                                                                           \
    load_lds16((src) + (c)*16384, (dst) + (c)*2048);                             \
    load_lds16((src) + ((c) + 1) * 16384, (dst) + ((c) + 1) * 2048);             \
  } while (0)

#define RDA2(dst, buf, ibase)                                                    \
  _Pragma("unroll") for (int i = 0; i < 2; ++i) {                                \
    dst[i][0] = *(const bf16x8*)&As[(buf)*8192 + a0 + ((ibase) + i) * 1024];     \
    dst[i][1] = *(const bf16x8*)&As[(buf)*8192 + a1 + ((ibase) + i) * 1024];     \
  }
#define RDB2(dst, buf, jbase)                                                    \
  _Pragma("unroll") for (int j = 0; j < 2; ++j) {                                \
    dst[j][0] = *(const bf16x8*)&Bs[(buf)*8192 + b0 + ((jbase) + j) * 1024];     \
    dst[j][1] = *(const bf16x8*)&Bs[(buf)*8192 + b1 + ((jbase) + j) * 1024];     \
  }

#define MFQ2(Af, Bf, I0, J0)                                                     \
  _Pragma("unroll") for (int i = 0; i < 2; ++i) _Pragma("unroll")                \
      for (int j = 0; j < 2; ++j) {                                              \
    acc[(I0) + i][(J0) + j] =                                                    \
        MFMA_16x16x32(Af[i][0], Bf[j][0], acc[(I0) + i][(J0) + j]);              \
    acc[(I0) + i][(J0) + j] =                                                    \
        MFMA_16x16x32(Af[i][1], Bf[j][1], acc[(I0) + i][(J0) + j]);              \
  }

#define GEMM_SETUP(Ap, Wp)                                                       \
  __shared__ bf16_t As[2 * 8192];                                                \
  __shared__ bf16_t Bs[2 * 8192];                                                \
  const int t = threadIdx.x;                                                     \
  const int w = t >> 6, L = t & 63;                                              \
  const int wm = w >> 1, wn = w & 1;                                             \
  const int lrow = L & 15, lq = L >> 4;                                          \
  const int srow = t >> 3;                                                       \
  const int sslot = (t & 7) ^ (srow & 7);                                        \
  const bf16_t* ga = (Ap) + (size_t)(m0 + srow) * 512 + sslot * 8;               \
  const bf16_t* gb = (Wp) + (size_t)(n0 + srow) * 512 + sslot * 8;               \
  bf16_t* la = As + t * 8;                                                       \
  bf16_t* lb = Bs + t * 8;                                                       \
  const int m8 = (lrow & 7) * 8;                                                 \
  const int a0 = (wm * 64 + lrow) * 64 + ((lq * 8) ^ m8);                        \
  const int a1 = (wm * 64 + lrow) * 64 + ((32 + lq * 8) ^ m8);                   \
  const int b0 = (wn * 64 + lrow) * 64 + ((lq * 8) ^ m8);                        \
  const int b1 = (wn * 64 + lrow) * 64 + ((32 + lq * 8) ^ m8);

// prologue: A0->buf0, B0->buf0, A1->buf1 (12 loads); gate to A0/B0 landed
#define PROLOGUE()                                                               \
  STG2(ga, la, 0); STG2(ga, la, 2);                                              \
  STG2(gb, lb, 0); STG2(gb, lb, 2);                                              \
  STG2(ga + 64, la + 8192, 0); STG2(ga + 64, la + 8192, 2);                      \
  asm volatile("s_waitcnt vmcnt(4)" ::: "memory");                               \
  __builtin_amdgcn_s_barrier();                                                  \
  __builtin_amdgcn_sched_barrier(0);

#define HALF_STEADY(CUR, LBDST, LADST, GBP, GAP)                                 \
  {                                                                              \
    bf16x8 fal[2][2], fbl[2][2], fah[2][2], fbh[2][2];                           \
    RDA2(fal, CUR, 0); RDB2(fbl, CUR, 0); RDB2(fbh, CUR, 2);                     \
    STG2(GBP, LBDST, 0);                                                         \
    PH_OPEN(); MFQ2(fal, fbl, 0, 0); PH_CLOSE();                                 \
    RDA2(fah, CUR, 2);                                                           \
    STG2(GBP, LBDST, 2);                                                         \
    PH_OPEN(); MFQ2(fal, fbh, 0, 2); PH_CLOSE();                                 \
    STG2(GAP, LADST, 0);                                                         \
    PH_OPEN(); MFQ2(fah, fbh, 2, 2); PH_CLOSE();                                 \
    STG2(GAP, LADST, 2);                                                         \
    PH_OPEN(); MFQ2(fah, fbl, 2, 0); GATE4();                                    \
  }

#define GEMM_LOOP()                                                              \
  {                                                                              \
    const bf16_t* gA = ga + 128; /* A(2) */                                      \
    const bf16_t* gB = gb + 64;  /* B(1) */                                      \
    _Pragma("unroll 1") for (int G = 0; G < 3; ++G) {                            \
      HALF_STEADY(0, lb + 8192, la, gB, gA)                                      \
      HALF_STEADY(1, lb, la + 8192, gB + 64, gA + 64)                            \
      gA += 128; gB += 128;                                                      \
    }                                                                            \
    { /* tail tile 6 (buf0): stage only B7->buf1; drain all at gate */           \
      bf16x8 fal[2][2], fbl[2][2], fah[2][2], fbh[2][2];                         \
      RDA2(fal, 0, 0); RDB2(fbl, 0, 0); RDB2(fbh, 0, 2);                         \
      STG2(gB, lb + 8192, 0);                                                    \
      PH_OPEN(); MFQ2(fal, fbl, 0, 0); PH_CLOSE();                               \
      RDA2(fah, 0, 2);                                                           \
      STG2(gB, lb + 8192, 2);                                                    \
      PH_OPEN(); MFQ2(fal, fbh, 0, 2); PH_CLOSE();                               \
      PH_OPEN(); MFQ2(fah, fbh, 2, 2); PH_CLOSE();                               \
      PH_OPEN(); MFQ2(fah, fbl, 2, 0); GATE0();                                  \
    }                                                                            \
    { /* tail tile 7 (buf1): no staging, no gate */                              \
      bf16x8 fal[2][2], fbl[2][2], fah[2][2], fbh[2][2];                         \
      RDA2(fal, 1, 0); RDB2(fbl, 1, 0); RDB2(fbh, 1, 2);                         \
      PH_OPEN(); MFQ2(fal, fbl, 0, 0); PH_CLOSE();                               \
      RDA2(fah, 1, 2);                                                           \
      PH_OPEN(); MFQ2(fal, fbh, 0, 2); PH_CLOSE();                               \
      PH_OPEN(); MFQ2(fah, fbh, 2, 2); PH_CLOSE();                               \
      PH_OPEN(); MFQ2(fah, fbl, 2, 0);                                           \
      __builtin_amdgcn_s_setprio(0);                                             \
      __builtin_amdgcn_sched_barrier(0);                                         \
    }                                                                            \
  }

// ---------------------------------------------------------------------------
// QKV GEMM: 128x128 tiles, 3072 blocks (12/CU sequential, 2 resident).
// XCD swizzle: 384 consecutive wgs per XCD; nt-inner for A-panel L2 reuse.
// q is pre-scaled by scale*log2e (exp2-direct softmax downstream).
// ---------------------------------------------------------------------------
__global__ __launch_bounds__(256, 2) void qkv_gemm128_k(
    const bf16_t* __restrict__ A, const bf16_t* __restrict__ W,
    const float* __restrict__ Bvec,
    bf16_t* __restrict__ qws, bf16_t* __restrict__ kws, bf16_t* __restrict__ vws) {
  const int id = blockIdx.x;                   // 0..3071
  const int wg = (id & 7) * 384 + (id >> 3);   // bijective XCD swizzle
  const int mt = wg / 12, nt = wg % 12;
  const int m0 = mt * 128, n0 = nt * 128;

  GEMM_SETUP(A, W);

  f32x4 acc[4][4];
#pragma unroll
  for (int jj = 0; jj < 4; ++jj) {
    float bv = Bvec[n0 + wn * 64 + jj * 16 + lrow];
#pragma unroll
    for (int i = 0; i < 4; ++i) acc[i][jj] = (f32x4){bv, bv, bv, bv};
  }

  PROLOGUE();
  GEMM_LOOP();

  const int col0 = n0 + wn * 64;               // 64-aligned -> s uniform/wave
  const int s = col0 >> 9;
  bf16_t* dst = (s == 0) ? qws : (s == 1) ? kws : vws;
  const float mul = (s == 0) ? 0.17677669529663687f * LOG2E : 1.0f;
#pragma unroll
  for (int jj = 0; jj < 4; ++jj) {
    int o = col0 + jj * 16 + lrow;
    int rem = o & 511;
    int hh = rem >> 5, d = rem & 31;
#pragma unroll
    for (int i = 0; i < 4; ++i) {
#pragma unroll
      for (int r = 0; r < 4; ++r) {
        int m = m0 + wm * 64 + i * 16 + lq * 4 + r;
        int b = m >> 8, n = m & 255;
        dst[(size_t)(((b * 16 + hh) * 256 + n) << 5) + d] =
            (bf16_t)(acc[i][jj][r] * mul);
      }
    }
  }
}

// ---------------------------------------------------------------------------
// Proj GEMM 128x128: 256 mt x 4 nt = 1024 blocks (4/CU, 2 resident).
// ---------------------------------------------------------------------------
__global__ __launch_bounds__(256, 2) void proj_gemm128_k(
    const bf16_t* __restrict__ A, const bf16_t* __restrict__ W,
    const float* __restrict__ Bvec, float* __restrict__ out) {
  const int id = blockIdx.x;                   // 0..1023
  const int wg = (id & 7) * 128 + (id >> 3);
  const int mt = wg >> 2, nt = wg & 3;
  const int m0 = mt * 128, n0 = nt * 128;

  GEMM_SETUP(A, W);

  f32x4 acc[4][4];
#pragma unroll
  for (int jj = 0; jj < 4; ++jj) {
    float bv = Bvec[n0 + wn * 64 + jj * 16 + lrow];
#pragma unroll
    for (int i = 0; i < 4; ++i) acc[i][jj] = (f32x4){bv, bv, bv, bv};
  }

  PROLOGUE();
  GEMM_LOOP();

#pragma unroll
  for (int jj = 0; jj < 4; ++jj) {
    int o = n0 + wn * 64 + jj * 16 + lrow;
#pragma unroll
    for (int i = 0; i < 4; ++i) {
#pragma unroll
      for (int r = 0; r < 4; ++r) {
        int m = m0 + wm * 64 + i * 16 + lq * 4 + r;
        out[(size_t)m * 512 + o] = acc[i][jj][r];
      }
    }
  }
}

// ---------------------------------------------------------------------------
// Attention, swapped-QK^T + in-register P. VALU cuts this round:
//  - exp2-direct: q and bias pre-scaled by log2e -> raw v_exp_f32 (2^x),
//    deletes 64 v_mul per s-iter.
//  - defer-norm: pack UNNORMALIZED e; normalize O at store via 4 bpermuted
//    inv values + 8 muls (deletes another 64 v_mul per s-iter).
//  - f32x4 vector sum accumulation (4 indep dep chains vs 63-add serial).
// ---------------------------------------------------------------------------
__global__ __launch_bounds__(256) void attn_k(
    const bf16_t* __restrict__ qws, const bf16_t* __restrict__ kws,
    const bf16_t* __restrict__ vws, const float* __restrict__ biasws,
    bf16_t* __restrict__ aows) {
  __shared__ __align__(16) bf16_t Vs[32 * 264];  // V^T: [d][n], padded

  const int bh = blockIdx.x;             // 0..2047
  const int h = bh & 15, b = bh >> 4;

  const int t = threadIdx.x;
  const int w = t >> 6, L = t & 63;
  const int lrow = L & 15, lq = L >> 4;

  const bf16_t* kbase = kws + (size_t)bh * 8192;
  const bf16_t* vbase = vws + (size_t)bh * 8192;

  // V transpose into LDS, once per (b,h)
#pragma unroll
  for (int c = 0; c < 4; c++) {
    bf16x8 vv = *(const bf16x8*)(vbase + t * 32 + c * 8);
#pragma unroll
    for (int j = 0; j < 8; j++) Vs[(c * 8 + j) * 264 + t] = vv[j];
  }
  __syncthreads();

  // bpermute byte-indices for P-fragment assembly (per-lane constants)
  const int idxA = ((2 * (lq & 1)) * 16 + lrow) * 4;
  const int idxB = idxA + 64;
  const bool gsel = (lq < 2);

  const float* bbw = biasws + h * 65536 + (w * 4) * 4096;

#pragma unroll 1
  for (int s = 0; s < 4; ++s) {
    const int qrow0 = w * 64 + s * 16;
    const bf16_t* qbase = qws + (size_t)bh * 8192 + qrow0 * 32;
    bf16x8 qf = *(const bf16x8*)(qbase + lrow * 32 + lq * 8);
    const float* bb = bbw + s * 4096;

    // S' = log2e*(qk*scale + bias): swapped MFMA, bias as accumulator init
    f32x4 S[16];
#pragma unroll
    for (int ct = 0; ct < 16; ct++) {
      bf16x8 kf = *(const bf16x8*)(kbase + (ct * 16 + lrow) * 32 + lq * 8);
      f32x4 bi = *(const f32x4*)(bb + ct * 256 + L * 4);
      S[ct] = MFMA_16x16x32(kf, qf, bi);
    }

    // e = 2^S' (exp2-direct); vector sum accumulation
    f32x4 sv = {};
#pragma unroll
    for (int ct = 0; ct < 16; ct++) {
#pragma unroll
      for (int r = 0; r < 4; r++) {
        float e;
        asm("v_exp_f32 %0, %1" : "=v"(e) : "v"(S[ct][r]));
        S[ct][r] = e;
      }
      sv += S[ct];
    }
    float sm = (sv[0] + sv[1]) + (sv[2] + sv[3]);
    sm += __shfl_xor(sm, 16, 64);
    sm += __shfl_xor(sm, 32, 64);
    const float inv = 1.0f / sm;

    // pack UNNORMALIZED e -> bf16 dword pairs
    int pd[16][2];
#pragma unroll
    for (int ct = 0; ct < 16; ct++) {
#pragma unroll
      for (int j = 0; j < 2; j++) {
        int d;
        asm("v_cvt_pk_bf16_f32 %0, %1, %2"
            : "=v"(d) : "v"(S[ct][2 * j]), "v"(S[ct][2 * j + 1]));
        pd[ct][j] = d;
      }
    }

    // PV: assemble A-fragments cross-lane, MFMA against Vs
    f32x4 O0 = {}, O1 = {};
#pragma unroll
    for (int kt = 0; kt < 8; kt++) {
      int rA0 = __builtin_amdgcn_ds_bpermute(idxA, pd[2 * kt][0]);
      int rA1 = __builtin_amdgcn_ds_bpermute(idxA, pd[2 * kt][1]);
      int rA2 = __builtin_amdgcn_ds_bpermute(idxB, pd[2 * kt][0]);
      int rA3 = __builtin_amdgcn_ds_bpermute(idxB, pd[2 * kt][1]);
      int rB0 = __builtin_amdgcn_ds_bpermute(idxA, pd[2 * kt + 1][0]);
      int rB1 = __builtin_amdgcn_ds_bpermute(idxA, pd[2 * kt + 1][1]);
      int rB2 = __builtin_amdgcn_ds_bpermute(idxB, pd[2 * kt + 1][0]);
      int rB3 = __builtin_amdgcn_ds_bpermute(idxB, pd[2 * kt + 1][1]);
      int4 Di;
      Di.x = gsel ? rA0 : rB0;
      Di.y = gsel ? rA1 : rB1;
      Di.z = gsel ? rA2 : rB2;
      Di.w = gsel ? rA3 : rB3;
      bf16x8 pf = *reinterpret_cast<bf16x8*>(&Di);
      bf16x8 v0 = *(const bf16x8*)&Vs[lrow * 264 + kt * 32 + lq * 8];
      bf16x8 v1 = *(const bf16x8*)&Vs[(16 + lrow) * 264 + kt * 32 + lq * 8];
      O0 = MFMA_16x16x32(pf, v0, O0);
      O1 = MFMA_16x16x32(pf, v1, O1);
    }

    // normalize O at store: inv lives at lane lrow=q; O row q = lq*4+r
    bf16_t* obase = aows + (size_t)(b * 256 + qrow0) * 512 + h * 32;
#pragma unroll
    for (int r = 0; r < 4; r++) {
      float invO = __int_as_float(
          __builtin_amdgcn_ds_bpermute((lq * 4 + r) * 4, __float_as_int(inv)));
      int rl = lq * 4 + r;
      obase[rl * 512 + lrow] = (bf16_t)(O0[r] * invO);
      obase[rl * 512 + 16 + lrow] = (bf16_t)(O1[r] * invO);
    }
  }
}

// ---------------------------------------------------------------------------
extern "C" void kernel_launch(void* const* d_in, const int* in_sizes, int n_in,
                              void* d_out, int out_size, void* d_ws, size_t ws_size,
                              hipStream_t stream) {
  (void)in_sizes; (void)n_in; (void)out_size; (void)ws_size;
  const float* x      = (const float*)d_in[0];
  const float* qkv_w  = (const float*)d_in[1];
  const float* qkv_b  = (const float*)d_in[2];
  const float* proj_w = (const float*)d_in[3];
  const float* proj_b = (const float*)d_in[4];
  const float* table  = (const float*)d_in[5];
  const int*   rel    = (const int*)d_in[6];

  const size_t QKV_ELEMS = 16777216;  // 128*16*256*32
  bf16_t* qws     = (bf16_t*)d_ws;
  bf16_t* kws     = qws + QKV_ELEMS;
  bf16_t* vws     = kws + QKV_ELEMS;
  float*  biasws  = (float*)(vws + QKV_ELEMS);
  bf16_t* wqkvbf  = (bf16_t*)(biasws + 1048576);
  bf16_t* wprojbf = wqkvbf + 786432;
  bf16_t* xbf     = wprojbf + 262144;  // aliased with aows (liveness disjoint)
  bf16_t* aows    = xbf;
  float*  out     = (float*)d_out;

  prep_k<<<12800, 256, 0, stream>>>(x, qkv_w, proj_w, table, rel,
                                    xbf, wqkvbf, wprojbf, biasws);
  qkv_gemm128_k<<<3072, 256, 0, stream>>>(xbf, wqkvbf, qkv_b, qws, kws, vws);
  attn_k<<<2048, 256, 0, stream>>>(qws, kws, vws, biasws, aows);
  proj_gemm128_k<<<1024, 256, 0, stream>>>(aows, wprojbf, proj_b, out);
}

// Round 8
// 302.657 us; speedup vs baseline: 1.0673x; 1.0673x over previous
//
#include <hip/hip_runtime.h>

typedef __bf16 bf16_t;
typedef __bf16 bf16x8 __attribute__((ext_vector_type(8)));
typedef float f32x4 __attribute__((ext_vector_type(4)));

#define MFMA_16x16x32(a, b, c) __builtin_amdgcn_mfma_f32_16x16x32_bf16((a), (b), (c), 0, 0, 0)

__device__ inline bf16x8 cvt8(const float* __restrict__ p) {
  bf16x8 r;
#pragma unroll
  for (int j = 0; j < 8; j++) r[j] = (bf16_t)p[j];
  return r;
}

// async 16B global->LDS DMA: LDS dest = (wave-uniform) base + lane*16B
__device__ inline void load_lds16(const bf16_t* g, bf16_t* l) {
  __builtin_amdgcn_global_load_lds(
      (const __attribute__((address_space(1))) void*)g,
      (__attribute__((address_space(3))) void*)l, 16, 0, 0);
}

// ---------------------------------------------------------------------------
// prep_k: fused convert (fp32->bf16 for x, qkv_w, proj_w) + bias gather.
// bias layout (TRANSPOSED fragment-major for swapped QK^T), UNSCALED:
//   biasws[h*65536 + qb*4096 + ct*256 + L*4 + r]
//     = bias[h][q = qb*16 + (L&15)][k = ct*16 + (L>>4)*4 + r]
// ---------------------------------------------------------------------------
__global__ __launch_bounds__(256) void prep_k(
    const float* __restrict__ x, const float* __restrict__ qkv_w,
    const float* __restrict__ proj_w, const float* __restrict__ table,
    const int* __restrict__ rel,
    bf16_t* __restrict__ xbf, bf16_t* __restrict__ wqkvbf,
    bf16_t* __restrict__ wprojbf, float* __restrict__ biasws) {
  const int bid = blockIdx.x;
  if (bid < 8704) {
    size_t base = ((size_t)bid * 256 + threadIdx.x) * 8;
    if (base < 16777216) {
      *(bf16x8*)(xbf + base) = cvt8(x + base);
    } else if (base < 17563648) {
      size_t o = base - 16777216;
      *(bf16x8*)(wqkvbf + o) = cvt8(qkv_w + o);
    } else {
      size_t o = base - 17563648;
      *(bf16x8*)(wprojbf + o) = cvt8(proj_w + o);
    }
  } else {
    int idx = (bid - 8704) * 256 + threadIdx.x;  // 0 .. 1048576
    int h = idx >> 16;
    int rem = idx & 65535;
    int qb = rem >> 12;
    int ct = (rem >> 8) & 15;
    int L = (rem >> 2) & 63;
    int r = idx & 3;
    int q = qb * 16 + (L & 15);
    int k = ct * 16 + (L >> 4) * 4 + r;
    biasws[idx] = table[rel[q * 256 + k] * 16 + h];
  }
}

// ---------------------------------------------------------------------------
// 128x128-tile 4-phase GEMM core, drain-at-phase-end schedule (r7, kept).
// 4 waves (2M x 2N), per-wave 64x64 output = acc[4][4]. LDS 64 KiB ->
// 2 blocks/CU (two barrier groups cover each other's gate/drain stalls).
// ---------------------------------------------------------------------------
#define PH_OPEN() __builtin_amdgcn_s_setprio(1)

#define PH_CLOSE()                                        \
  do {                                                    \
    __builtin_amdgcn_s_setprio(0);                        \
    asm volatile("s_waitcnt lgkmcnt(0)" ::: "memory");    \
    __builtin_amdgcn_sched_barrier(0);                    \
    __builtin_amdgcn_s_barrier();                         \
    __builtin_amdgcn_sched_barrier(0);                    \
  } while (0)

#define GATE4()                                           \
  do {                                                    \
    __builtin_amdgcn_s_setprio(0);                        \
    asm volatile("s_waitcnt vmcnt(4)" ::: "memory");      \
    __builtin_amdgcn_s_barrier();                         \
    __builtin_amdgcn_sched_barrier(0);                    \
  } while (0)

#define GATE0()                                           \
  do {                                                    \
    __builtin_amdgcn_s_setprio(0);                        \
    asm volatile("s_waitcnt vmcnt(0)" ::: "memory");      \
    __builtin_amdgcn_s_barrier();                         \
    __builtin_amdgcn_sched_barrier(0);                    \
  } while (0)

// stage rows [c*32, c*32+64) of one 128x64 K-tile (256 thr: 32 rows/load)
#define STG2(src, dst, c)                                                        \
  do {                                                                           \
    load_lds16((src) + (c)*16384, (dst) + (c)*2048);                             \
    load_lds16((src) + ((c) + 1) * 16384, (dst) + ((c) + 1) * 2048);             \
  } while (0)

#define RDA2(dst, buf, ibase)                                                    \
  _Pragma("unroll") for (int i = 0; i < 2; ++i) {                                \
    dst[i][0] = *(const bf16x8*)&As[(buf)*8192 + a0 + ((ibase) + i) * 1024];     \
    dst[i][1] = *(const bf16x8*)&As[(buf)*8192 + a1 + ((ibase) + i) * 1024];     \
  }
#define RDB2(dst, buf, jbase)                                                    \
  _Pragma("unroll") for (int j = 0; j < 2; ++j) {                                \
    dst[j][0] = *(const bf16x8*)&Bs[(buf)*8192 + b0 + ((jbase) + j) * 1024];     \
    dst[j][1] = *(const bf16x8*)&Bs[(buf)*8192 + b1 + ((jbase) + j) * 1024];     \
  }

#define MFQ2(Af, Bf, I0, J0)                                                     \
  _Pragma("unroll") for (int i = 0; i < 2; ++i) _Pragma("unroll")                \
      for (int j = 0; j < 2; ++j) {                                              \
    acc[(I0) + i][(J0) + j] =                                                    \
        MFMA_16x16x32(Af[i][0], Bf[j][0], acc[(I0) + i][(J0) + j]);              \
    acc[(I0) + i][(J0) + j] =                                                    \
        MFMA_16x16x32(Af[i][1], Bf[j][1], acc[(I0) + i][(J0) + j]);              \
  }

#define GEMM_SETUP(Ap, Wp)                                                       \
  __shared__ bf16_t As[2 * 8192];                                                \
  __shared__ bf16_t Bs[2 * 8192];                                                \
  const int t = threadIdx.x;                                                     \
  const int w = t >> 6, L = t & 63;                                              \
  const int wm = w >> 1, wn = w & 1;                                             \
  const int lrow = L & 15, lq = L >> 4;                                          \
  const int srow = t >> 3;                                                       \
  const int sslot = (t & 7) ^ (srow & 7);                                        \
  const bf16_t* ga = (Ap) + (size_t)(m0 + srow) * 512 + sslot * 8;               \
  const bf16_t* gb = (Wp) + (size_t)(n0 + srow) * 512 + sslot * 8;               \
  bf16_t* la = As + t * 8;                                                       \
  bf16_t* lb = Bs + t * 8;                                                       \
  const int m8 = (lrow & 7) * 8;                                                 \
  const int a0 = (wm * 64 + lrow) * 64 + ((lq * 8) ^ m8);                        \
  const int a1 = (wm * 64 + lrow) * 64 + ((32 + lq * 8) ^ m8);                   \
  const int b0 = (wn * 64 + lrow) * 64 + ((lq * 8) ^ m8);                        \
  const int b1 = (wn * 64 + lrow) * 64 + ((32 + lq * 8) ^ m8);

// prologue: A0->buf0, B0->buf0, A1->buf1 (12 loads); gate to A0/B0 landed
#define PROLOGUE()                                                               \
  STG2(ga, la, 0); STG2(ga, la, 2);                                              \
  STG2(gb, lb, 0); STG2(gb, lb, 2);                                              \
  STG2(ga + 64, la + 8192, 0); STG2(ga + 64, la + 8192, 2);                      \
  asm volatile("s_waitcnt vmcnt(4)" ::: "memory");                               \
  __builtin_amdgcn_s_barrier();                                                  \
  __builtin_amdgcn_sched_barrier(0);

#define HALF_STEADY(CUR, LBDST, LADST, GBP, GAP)                                 \
  {                                                                              \
    bf16x8 fal[2][2], fbl[2][2], fah[2][2], fbh[2][2];                           \
    RDA2(fal, CUR, 0); RDB2(fbl, CUR, 0); RDB2(fbh, CUR, 2);                     \
    STG2(GBP, LBDST, 0);                                                         \
    PH_OPEN(); MFQ2(fal, fbl, 0, 0); PH_CLOSE();                                 \
    RDA2(fah, CUR, 2);                                                           \
    STG2(GBP, LBDST, 2);                                                         \
    PH_OPEN(); MFQ2(fal, fbh, 0, 2); PH_CLOSE();                                 \
    STG2(GAP, LADST, 0);                                                         \
    PH_OPEN(); MFQ2(fah, fbh, 2, 2); PH_CLOSE();                                 \
    STG2(GAP, LADST, 2);                                                         \
    PH_OPEN(); MFQ2(fah, fbl, 2, 0); GATE4();                                    \
  }

#define GEMM_LOOP()                                                              \
  {                                                                              \
    const bf16_t* gA = ga + 128; /* A(2) */                                      \
    const bf16_t* gB = gb + 64;  /* B(1) */                                      \
    _Pragma("unroll 1") for (int G = 0; G < 3; ++G) {                            \
      HALF_STEADY(0, lb + 8192, la, gB, gA)                                      \
      HALF_STEADY(1, lb, la + 8192, gB + 64, gA + 64)                            \
      gA += 128; gB += 128;                                                      \
    }                                                                            \
    { /* tail tile 6 (buf0): stage only B7->buf1; drain all at gate */           \
      bf16x8 fal[2][2], fbl[2][2], fah[2][2], fbh[2][2];                         \
      RDA2(fal, 0, 0); RDB2(fbl, 0, 0); RDB2(fbh, 0, 2);                         \
      STG2(gB, lb + 8192, 0);                                                    \
      PH_OPEN(); MFQ2(fal, fbl, 0, 0); PH_CLOSE();                               \
      RDA2(fah, 0, 2);                                                           \
      STG2(gB, lb + 8192, 2);                                                    \
      PH_OPEN(); MFQ2(fal, fbh, 0, 2); PH_CLOSE();                               \
      PH_OPEN(); MFQ2(fah, fbh, 2, 2); PH_CLOSE();                               \
      PH_OPEN(); MFQ2(fah, fbl, 2, 0); GATE0();                                  \
    }                                                                            \
    { /* tail tile 7 (buf1): no staging, no gate */                              \
      bf16x8 fal[2][2], fbl[2][2], fah[2][2], fbh[2][2];                         \
      RDA2(fal, 1, 0); RDB2(fbl, 1, 0); RDB2(fbh, 1, 2);                         \
      PH_OPEN(); MFQ2(fal, fbl, 0, 0); PH_CLOSE();                               \
      RDA2(fah, 1, 2);                                                           \
      PH_OPEN(); MFQ2(fal, fbh, 0, 2); PH_CLOSE();                               \
      PH_OPEN(); MFQ2(fah, fbh, 2, 2); PH_CLOSE();                               \
      PH_OPEN(); MFQ2(fah, fbl, 2, 0);                                           \
      __builtin_amdgcn_s_setprio(0);                                             \
      __builtin_amdgcn_sched_barrier(0);                                         \
    }                                                                            \
  }

// ---------------------------------------------------------------------------
// QKV GEMM: 128x128 tiles, 3072 blocks (12/CU, 2 resident).
// ---------------------------------------------------------------------------
__global__ __launch_bounds__(256, 2) void qkv_gemm128_k(
    const bf16_t* __restrict__ A, const bf16_t* __restrict__ W,
    const float* __restrict__ Bvec,
    bf16_t* __restrict__ qws, bf16_t* __restrict__ kws, bf16_t* __restrict__ vws) {
  const int id = blockIdx.x;                   // 0..3071
  const int wg = (id & 7) * 384 + (id >> 3);   // bijective XCD swizzle
  const int mt = wg / 12, nt = wg % 12;
  const int m0 = mt * 128, n0 = nt * 128;

  GEMM_SETUP(A, W);

  f32x4 acc[4][4];
#pragma unroll
  for (int jj = 0; jj < 4; ++jj) {
    float bv = Bvec[n0 + wn * 64 + jj * 16 + lrow];
#pragma unroll
    for (int i = 0; i < 4; ++i) acc[i][jj] = (f32x4){bv, bv, bv, bv};
  }

  PROLOGUE();
  GEMM_LOOP();

  const int col0 = n0 + wn * 64;               // 64-aligned -> s uniform/wave
  const int s = col0 >> 9;
  bf16_t* dst = (s == 0) ? qws : (s == 1) ? kws : vws;
  const float mul = (s == 0) ? 0.17677669529663687f : 1.0f;  // 1/sqrt(32) on q
#pragma unroll
  for (int jj = 0; jj < 4; ++jj) {
    int o = col0 + jj * 16 + lrow;
    int rem = o & 511;
    int hh = rem >> 5, d = rem & 31;
#pragma unroll
    for (int i = 0; i < 4; ++i) {
#pragma unroll
      for (int r = 0; r < 4; ++r) {
        int m = m0 + wm * 64 + i * 16 + lq * 4 + r;
        int b = m >> 8, n = m & 255;
        dst[(size_t)(((b * 16 + hh) * 256 + n) << 5) + d] =
            (bf16_t)(acc[i][jj][r] * mul);
      }
    }
  }
}

// ---------------------------------------------------------------------------
// Proj GEMM 128x128: 256 mt x 4 nt = 1024 blocks (4/CU, 2 resident).
// ---------------------------------------------------------------------------
__global__ __launch_bounds__(256, 2) void proj_gemm128_k(
    const bf16_t* __restrict__ A, const bf16_t* __restrict__ W,
    const float* __restrict__ Bvec, float* __restrict__ out) {
  const int id = blockIdx.x;                   // 0..1023
  const int wg = (id & 7) * 128 + (id >> 3);
  const int mt = wg >> 2, nt = wg & 3;
  const int m0 = mt * 128, n0 = nt * 128;

  GEMM_SETUP(A, W);

  f32x4 acc[4][4];
#pragma unroll
  for (int jj = 0; jj < 4; ++jj) {
    float bv = Bvec[n0 + wn * 64 + jj * 16 + lrow];
#pragma unroll
    for (int i = 0; i < 4; ++i) acc[i][jj] = (f32x4){bv, bv, bv, bv};
  }

  PROLOGUE();
  GEMM_LOOP();

#pragma unroll
  for (int jj = 0; jj < 4; ++jj) {
    int o = n0 + wn * 64 + jj * 16 + lrow;
#pragma unroll
    for (int i = 0; i < 4; ++i) {
#pragma unroll
      for (int r = 0; r < 4; ++r) {
        int m = m0 + wm * 64 + i * 16 + lq * 4 + r;
        out[(size_t)m * 512 + o] = acc[i][jj][r];
      }
    }
  }
}

// ---------------------------------------------------------------------------
// Attention: high-TLP grid (8192 blocks = bh x 64-row strip, XCD-swizzled,
// r5's proven TLP) + in-register P (r6's verified cvt_pk/bpermute path,
// inv folded pre-pack). LDS = Vs only (16.9 KB) -> ~8 blocks/CU co-resident;
// the serialized K/bias global loads hide behind wave-level parallelism.
// ---------------------------------------------------------------------------
__global__ __launch_bounds__(256) void attn_k(
    const bf16_t* __restrict__ qws, const bf16_t* __restrict__ kws,
    const bf16_t* __restrict__ vws, const float* __restrict__ biasws,
    bf16_t* __restrict__ aows) {
  __shared__ __align__(16) bf16_t Vs[32 * 264];  // V^T: [d][n], padded

  const int id = blockIdx.x;             // 0..8191
  const int xcd = id & 7;
  const int jj = id >> 3;                // 0..1023
  const int bh = (jj >> 2) * 8 + xcd;    // 0..2047
  const int strip = jj & 3;
  const int h = bh & 15, b = bh >> 4;

  const int t = threadIdx.x;
  const int w = t >> 6, L = t & 63;
  const int lrow = L & 15, lq = L >> 4;

  const bf16_t* kbase = kws + (size_t)bh * 8192;
  const bf16_t* vbase = vws + (size_t)bh * 8192;

  // V transpose into LDS
#pragma unroll
  for (int c = 0; c < 4; c++) {
    bf16x8 vv = *(const bf16x8*)(vbase + t * 32 + c * 8);
#pragma unroll
    for (int j = 0; j < 8; j++) Vs[(c * 8 + j) * 264 + t] = vv[j];
  }
  __syncthreads();

  // bpermute byte-indices for P-fragment assembly (per-lane constants)
  const int idxA = ((2 * (lq & 1)) * 16 + lrow) * 4;
  const int idxB = idxA + 64;
  const bool gsel = (lq < 2);

  const int qrow0 = strip * 64 + w * 16;
  const bf16_t* qbase = qws + (size_t)bh * 8192 + qrow0 * 32;
  bf16x8 qf = *(const bf16x8*)(qbase + lrow * 32 + lq * 8);
  const float* bb = biasws + h * 65536 + (strip * 4 + w) * 4096;

  // S^T tiles: swapped MFMA with transposed-bias accumulator init
  f32x4 S[16];
#pragma unroll
  for (int ct = 0; ct < 16; ct++) {
    bf16x8 kf = *(const bf16x8*)(kbase + (ct * 16 + lrow) * 32 + lq * 8);
    f32x4 bi = *(const f32x4*)(bb + ct * 256 + L * 4);
    S[ct] = MFMA_16x16x32(kf, qf, bi);
  }

  // softmax along k (lane-local row q = lane&15); vector sum accumulation
  f32x4 sv = {};
#pragma unroll
  for (int ct = 0; ct < 16; ct++) {
#pragma unroll
    for (int r = 0; r < 4; r++) S[ct][r] = __expf(S[ct][r]);
    sv += S[ct];
  }
  float sm = (sv[0] + sv[1]) + (sv[2] + sv[3]);
  sm += __shfl_xor(sm, 16, 64);
  sm += __shfl_xor(sm, 32, 64);
  const float inv = 1.0f / sm;

  // pack P*inv -> bf16 dword pairs (r6-verified)
  int pd[16][2];
#pragma unroll
  for (int ct = 0; ct < 16; ct++) {
#pragma unroll
    for (int j = 0; j < 2; j++) {
      float lo = S[ct][2 * j] * inv;
      float hi = S[ct][2 * j + 1] * inv;
      int d;
      asm("v_cvt_pk_bf16_f32 %0, %1, %2" : "=v"(d) : "v"(lo), "v"(hi));
      pd[ct][j] = d;
    }
  }

  // PV: assemble A-fragments cross-lane, MFMA against Vs
  f32x4 O0 = {}, O1 = {};
#pragma unroll
  for (int kt = 0; kt < 8; kt++) {
    int rA0 = __builtin_amdgcn_ds_bpermute(idxA, pd[2 * kt][0]);
    int rA1 = __builtin_amdgcn_ds_bpermute(idxA, pd[2 * kt][1]);
    int rA2 = __builtin_amdgcn_ds_bpermute(idxB, pd[2 * kt][0]);
    int rA3 = __builtin_amdgcn_ds_bpermute(idxB, pd[2 * kt][1]);
    int rB0 = __builtin_amdgcn_ds_bpermute(idxA, pd[2 * kt + 1][0]);
    int rB1 = __builtin_amdgcn_ds_bpermute(idxA, pd[2 * kt + 1][1]);
    int rB2 = __builtin_amdgcn_ds_bpermute(idxB, pd[2 * kt + 1][0]);
    int rB3 = __builtin_amdgcn_ds_bpermute(idxB, pd[2 * kt + 1][1]);
    int4 Di;
    Di.x = gsel ? rA0 : rB0;
    Di.y = gsel ? rA1 : rB1;
    Di.z = gsel ? rA2 : rB2;
    Di.w = gsel ? rA3 : rB3;
    bf16x8 pf = *reinterpret_cast<bf16x8*>(&Di);
    bf16x8 v0 = *(const bf16x8*)&Vs[lrow * 264 + kt * 32 + lq * 8];
    bf16x8 v1 = *(const bf16x8*)&Vs[(16 + lrow) * 264 + kt * 32 + lq * 8];
    O0 = MFMA_16x16x32(pf, v0, O0);
    O1 = MFMA_16x16x32(pf, v1, O1);
  }

  // O layout: row q = (lane>>4)*4+r, col d = lane&15 (P pre-normalized)
  bf16_t* obase = aows + (size_t)(b * 256 + qrow0) * 512 + h * 32;
#pragma unroll
  for (int r = 0; r < 4; r++) {
    int rl = lq * 4 + r;
    obase[rl * 512 + lrow] = (bf16_t)(O0[r]);
    obase[rl * 512 + 16 + lrow] = (bf16_t)(O1[r]);
  }
}

// ---------------------------------------------------------------------------
extern "C" void kernel_launch(void* const* d_in, const int* in_sizes, int n_in,
                              void* d_out, int out_size, void* d_ws, size_t ws_size,
                              hipStream_t stream) {
  (void)in_sizes; (void)n_in; (void)out_size; (void)ws_size;
  const float* x      = (const float*)d_in[0];
  const float* qkv_w  = (const float*)d_in[1];
  const float* qkv_b  = (const float*)d_in[2];
  const float* proj_w = (const float*)d_in[3];
  const float* proj_b = (const float*)d_in[4];
  const float* table  = (const float*)d_in[5];
  const int*   rel    = (const int*)d_in[6];

  const size_t QKV_ELEMS = 16777216;  // 128*16*256*32
  bf16_t* qws     = (bf16_t*)d_ws;
  bf16_t* kws     = qws + QKV_ELEMS;
  bf16_t* vws     = kws + QKV_ELEMS;
  float*  biasws  = (float*)(vws + QKV_ELEMS);
  bf16_t* wqkvbf  = (bf16_t*)(biasws + 1048576);
  bf16_t* wprojbf = wqkvbf + 786432;
  bf16_t* xbf     = wprojbf + 262144;  // aliased with aows (liveness disjoint)
  bf16_t* aows    = xbf;
  float*  out     = (float*)d_out;

  prep_k<<<12800, 256, 0, stream>>>(x, qkv_w, proj_w, table, rel,
                                    xbf, wqkvbf, wprojbf, biasws);
  qkv_gemm128_k<<<3072, 256, 0, stream>>>(xbf, wqkvbf, qkv_b, qws, kws, vws);
  attn_k<<<8192, 256, 0, stream>>>(qws, kws, vws, biasws, aows);
  proj_gemm128_k<<<1024, 256, 0, stream>>>(aows, wprojbf, proj_b, out);
}

// Round 9
// 279.440 us; speedup vs baseline: 1.1560x; 1.0831x over previous
//
#include <hip/hip_runtime.h>

typedef __bf16 bf16_t;
typedef __bf16 bf16x8 __attribute__((ext_vector_type(8)));
typedef float f32x4 __attribute__((ext_vector_type(4)));

#define MFMA_16x16x32(a, b, c) __builtin_amdgcn_mfma_f32_16x16x32_bf16((a), (b), (c), 0, 0, 0)

__device__ inline bf16x8 cvt8(const float* __restrict__ p) {
  bf16x8 r;
#pragma unroll
  for (int j = 0; j < 8; j++) r[j] = (bf16_t)p[j];
  return r;
}

// async 16B global->LDS DMA: LDS dest = (wave-uniform) base + lane*16B
__device__ inline void load_lds16(const bf16_t* g, bf16_t* l) {
  __builtin_amdgcn_global_load_lds(
      (const __attribute__((address_space(1))) void*)g,
      (__attribute__((address_space(3))) void*)l, 16, 0, 0);
}

// ---------------------------------------------------------------------------
// prep_k: fused convert (fp32->bf16 for x, qkv_w, proj_w) + bias gather.
// bias layout (r5 fragment-major, NON-transposed):
//   biasws[h*65536 + rb*4096 + ct*256 + L*4 + r]
//     = bias[h][row = rb*16 + (L>>4)*4 + r][col = ct*16 + (L&15)]
// ---------------------------------------------------------------------------
__global__ __launch_bounds__(256) void prep_k(
    const float* __restrict__ x, const float* __restrict__ qkv_w,
    const float* __restrict__ proj_w, const float* __restrict__ table,
    const int* __restrict__ rel,
    bf16_t* __restrict__ xbf, bf16_t* __restrict__ wqkvbf,
    bf16_t* __restrict__ wprojbf, float* __restrict__ biasws) {
  const int bid = blockIdx.x;
  if (bid < 8704) {
    size_t base = ((size_t)bid * 256 + threadIdx.x) * 8;
    if (base < 16777216) {
      *(bf16x8*)(xbf + base) = cvt8(x + base);
    } else if (base < 17563648) {
      size_t o = base - 16777216;
      *(bf16x8*)(wqkvbf + o) = cvt8(qkv_w + o);
    } else {
      size_t o = base - 17563648;
      *(bf16x8*)(wprojbf + o) = cvt8(proj_w + o);
    }
  } else {
    int idx = (bid - 8704) * 256 + threadIdx.x;  // 0 .. 1048576
    int h = idx >> 16;
    int rem = idx & 65535;
    int rb = rem >> 12;
    int ct = (rem >> 8) & 15;
    int L = (rem >> 2) & 63;
    int r = idx & 3;
    int row = rb * 16 + (L >> 4) * 4 + r;
    int col = ct * 16 + (L & 15);
    biasws[idx] = table[rel[row * 256 + col] * 16 + h];
  }
}

// ---------------------------------------------------------------------------
// 128x128-tile 4-phase GEMM core, drain-at-phase-end schedule (r7, kept).
// 4 waves (2M x 2N), per-wave 64x64 output = acc[4][4]. LDS 64 KiB ->
// 2 blocks/CU (two barrier groups cover each other's gate/drain stalls).
// ---------------------------------------------------------------------------
#define PH_OPEN() __builtin_amdgcn_s_setprio(1)

#define PH_CLOSE()                                        \
  do {                                                    \
    __builtin_amdgcn_s_setprio(0);                        \
    asm volatile("s_waitcnt lgkmcnt(0)" ::: "memory");    \
    __builtin_amdgcn_sched_barrier(0);                    \
    __builtin_amdgcn_s_barrier();                         \
    __builtin_amdgcn_sched_barrier(0);                    \
  } while (0)

#define GATE4()                                           \
  do {                                                    \
    __builtin_amdgcn_s_setprio(0);                        \
    asm volatile("s_waitcnt vmcnt(4)" ::: "memory");      \
    __builtin_amdgcn_s_barrier();                         \
    __builtin_amdgcn_sched_barrier(0);                    \
  } while (0)

#define GATE0()                                           \
  do {                                                    \
    __builtin_amdgcn_s_setprio(0);                        \
    asm volatile("s_waitcnt vmcnt(0)" ::: "memory");      \
    __builtin_amdgcn_s_barrier();                         \
    __builtin_amdgcn_sched_barrier(0);                    \
  } while (0)

// stage rows [c*32, c*32+64) of one 128x64 K-tile (256 thr: 32 rows/load)
#define STG2(src, dst, c)                                                        \
  do {                                                                           \
    load_lds16((src) + (c)*16384, (dst) + (c)*2048);                             \
    load_lds16((src) + ((c) + 1) * 16384, (dst) + ((c) + 1) * 2048);             \
  } while (0)

#define RDA2(dst, buf, ibase)                                                    \
  _Pragma("unroll") for (int i = 0; i < 2; ++i) {                                \
    dst[i][0] = *(const bf16x8*)&As[(buf)*8192 + a0 + ((ibase) + i) * 1024];     \
    dst[i][1] = *(const bf16x8*)&As[(buf)*8192 + a1 + ((ibase) + i) * 1024];     \
  }
#define RDB2(dst, buf, jbase)                                                    \
  _Pragma("unroll") for (int j = 0; j < 2; ++j) {                                \
    dst[j][0] = *(const bf16x8*)&Bs[(buf)*8192 + b0 + ((jbase) + j) * 1024];     \
    dst[j][1] = *(const bf16x8*)&Bs[(buf)*8192 + b1 + ((jbase) + j) * 1024];     \
  }

#define MFQ2(Af, Bf, I0, J0)                                                     \
  _Pragma("unroll") for (int i = 0; i < 2; ++i) _Pragma("unroll")                \
      for (int j = 0; j < 2; ++j) {                                              \
    acc[(I0) + i][(J0) + j] =                                                    \
        MFMA_16x16x32(Af[i][0], Bf[j][0], acc[(I0) + i][(J0) + j]);              \
    acc[(I0) + i][(J0) + j] =                                                    \
        MFMA_16x16x32(Af[i][1], Bf[j][1], acc[(I0) + i][(J0) + j]);              \
  }

#define GEMM_SETUP(Ap, Wp)                                                       \
  __shared__ bf16_t As[2 * 8192];                                                \
  __shared__ bf16_t Bs[2 * 8192];                                                \
  const int t = threadIdx.x;                                                     \
  const int w = t >> 6, L = t & 63;                                              \
  const int wm = w >> 1, wn = w & 1;                                             \
  const int lrow = L & 15, lq = L >> 4;                                          \
  const int srow = t >> 3;                                                       \
  const int sslot = (t & 7) ^ (srow & 7);                                        \
  const bf16_t* ga = (Ap) + (size_t)(m0 + srow) * 512 + sslot * 8;               \
  const bf16_t* gb = (Wp) + (size_t)(n0 + srow) * 512 + sslot * 8;               \
  bf16_t* la = As + t * 8;                                                       \
  bf16_t* lb = Bs + t * 8;                                                       \
  const int m8 = (lrow & 7) * 8;                                                 \
  const int a0 = (wm * 64 + lrow) * 64 + ((lq * 8) ^ m8);                        \
  const int a1 = (wm * 64 + lrow) * 64 + ((32 + lq * 8) ^ m8);                   \
  const int b0 = (wn * 64 + lrow) * 64 + ((lq * 8) ^ m8);                        \
  const int b1 = (wn * 64 + lrow) * 64 + ((32 + lq * 8) ^ m8);

// prologue: A0->buf0, B0->buf0, A1->buf1 (12 loads); gate to A0/B0 landed
#define PROLOGUE()                                                               \
  STG2(ga, la, 0); STG2(ga, la, 2);                                              \
  STG2(gb, lb, 0); STG2(gb, lb, 2);                                              \
  STG2(ga + 64, la + 8192, 0); STG2(ga + 64, la + 8192, 2);                      \
  asm volatile("s_waitcnt vmcnt(4)" ::: "memory");                               \
  __builtin_amdgcn_s_barrier();                                                  \
  __builtin_amdgcn_sched_barrier(0);

#define HALF_STEADY(CUR, LBDST, LADST, GBP, GAP)                                 \
  {                                                                              \
    bf16x8 fal[2][2], fbl[2][2], fah[2][2], fbh[2][2];                           \
    RDA2(fal, CUR, 0); RDB2(fbl, CUR, 0); RDB2(fbh, CUR, 2);                     \
    STG2(GBP, LBDST, 0);                                                         \
    PH_OPEN(); MFQ2(fal, fbl, 0, 0); PH_CLOSE();                                 \
    RDA2(fah, CUR, 2);                                                           \
    STG2(GBP, LBDST, 2);                                                         \
    PH_OPEN(); MFQ2(fal, fbh, 0, 2); PH_CLOSE();                                 \
    STG2(GAP, LADST, 0);                                                         \
    PH_OPEN(); MFQ2(fah, fbh, 2, 2); PH_CLOSE();                                 \
    STG2(GAP, LADST, 2);                                                         \
    PH_OPEN(); MFQ2(fah, fbl, 2, 0); GATE4();                                    \
  }

#define GEMM_LOOP()                                                              \
  {                                                                              \
    const bf16_t* gA = ga + 128; /* A(2) */                                      \
    const bf16_t* gB = gb + 64;  /* B(1) */                                      \
    _Pragma("unroll 1") for (int G = 0; G < 3; ++G) {                            \
      HALF_STEADY(0, lb + 8192, la, gB, gA)                                      \
      HALF_STEADY(1, lb, la + 8192, gB + 64, gA + 64)                            \
      gA += 128; gB += 128;                                                      \
    }                                                                            \
    { /* tail tile 6 (buf0): stage only B7->buf1; drain all at gate */           \
      bf16x8 fal[2][2], fbl[2][2], fah[2][2], fbh[2][2];                         \
      RDA2(fal, 0, 0); RDB2(fbl, 0, 0); RDB2(fbh, 0, 2);                         \
      STG2(gB, lb + 8192, 0);                                                    \
      PH_OPEN(); MFQ2(fal, fbl, 0, 0); PH_CLOSE();                               \
      RDA2(fah, 0, 2);                                                           \
      STG2(gB, lb + 8192, 2);                                                    \
      PH_OPEN(); MFQ2(fal, fbh, 0, 2); PH_CLOSE();                               \
      PH_OPEN(); MFQ2(fah, fbh, 2, 2); PH_CLOSE();                               \
      PH_OPEN(); MFQ2(fah, fbl, 2, 0); GATE0();                                  \
    }                                                                            \
    { /* tail tile 7 (buf1): no staging, no gate */                              \
      bf16x8 fal[2][2], fbl[2][2], fah[2][2], fbh[2][2];                         \
      RDA2(fal, 1, 0); RDB2(fbl, 1, 0); RDB2(fbh, 1, 2);                         \
      PH_OPEN(); MFQ2(fal, fbl, 0, 0); PH_CLOSE();                               \
      RDA2(fah, 1, 2);                                                           \
      PH_OPEN(); MFQ2(fal, fbh, 0, 2); PH_CLOSE();                               \
      PH_OPEN(); MFQ2(fah, fbh, 2, 2); PH_CLOSE();                               \
      PH_OPEN(); MFQ2(fah, fbl, 2, 0);                                           \
      __builtin_amdgcn_s_setprio(0);                                             \
      __builtin_amdgcn_sched_barrier(0);                                         \
    }                                                                            \
  }

// ---------------------------------------------------------------------------
// QKV GEMM: 128x128 tiles, 3072 blocks (12/CU, 2 resident).
// ---------------------------------------------------------------------------
__global__ __launch_bounds__(256, 2) void qkv_gemm128_k(
    const bf16_t* __restrict__ A, const bf16_t* __restrict__ W,
    const float* __restrict__ Bvec,
    bf16_t* __restrict__ qws, bf16_t* __restrict__ kws, bf16_t* __restrict__ vws) {
  const int id = blockIdx.x;                   // 0..3071
  const int wg = (id & 7) * 384 + (id >> 3);   // bijective XCD swizzle
  const int mt = wg / 12, nt = wg % 12;
  const int m0 = mt * 128, n0 = nt * 128;

  GEMM_SETUP(A, W);

  f32x4 acc[4][4];
#pragma unroll
  for (int jj = 0; jj < 4; ++jj) {
    float bv = Bvec[n0 + wn * 64 + jj * 16 + lrow];
#pragma unroll
    for (int i = 0; i < 4; ++i) acc[i][jj] = (f32x4){bv, bv, bv, bv};
  }

  PROLOGUE();
  GEMM_LOOP();

  const int col0 = n0 + wn * 64;               // 64-aligned -> s uniform/wave
  const int s = col0 >> 9;
  bf16_t* dst = (s == 0) ? qws : (s == 1) ? kws : vws;
  const float mul = (s == 0) ? 0.17677669529663687f : 1.0f;  // 1/sqrt(32) on q
#pragma unroll
  for (int jj = 0; jj < 4; ++jj) {
    int o = col0 + jj * 16 + lrow;
    int rem = o & 511;
    int hh = rem >> 5, d = rem & 31;
#pragma unroll
    for (int i = 0; i < 4; ++i) {
#pragma unroll
      for (int r = 0; r < 4; ++r) {
        int m = m0 + wm * 64 + i * 16 + lq * 4 + r;
        int b = m >> 8, n = m & 255;
        dst[(size_t)(((b * 16 + hh) * 256 + n) << 5) + d] =
            (bf16_t)(acc[i][jj][r] * mul);
      }
    }
  }
}

// ---------------------------------------------------------------------------
// Proj GEMM 128x128: 256 mt x 4 nt = 1024 blocks (4/CU, 2 resident).
// ---------------------------------------------------------------------------
__global__ __launch_bounds__(256, 2) void proj_gemm128_k(
    const bf16_t* __restrict__ A, const bf16_t* __restrict__ W,
    const float* __restrict__ Bvec, float* __restrict__ out) {
  const int id = blockIdx.x;                   // 0..1023
  const int wg = (id & 7) * 128 + (id >> 3);
  const int mt = wg >> 2, nt = wg & 3;
  const int m0 = mt * 128, n0 = nt * 128;

  GEMM_SETUP(A, W);

  f32x4 acc[4][4];
#pragma unroll
  for (int jj = 0; jj < 4; ++jj) {
    float bv = Bvec[n0 + wn * 64 + jj * 16 + lrow];
#pragma unroll
    for (int i = 0; i < 4; ++i) acc[i][jj] = (f32x4){bv, bv, bv, bv};
  }

  PROLOGUE();
  GEMM_LOOP();

#pragma unroll
  for (int jj = 0; jj < 4; ++jj) {
    int o = n0 + wn * 64 + jj * 16 + lrow;
#pragma unroll
    for (int i = 0; i < 4; ++i) {
#pragma unroll
      for (int r = 0; r < 4; ++r) {
        int m = m0 + wm * 64 + i * 16 + lq * 4 + r;
        out[(size_t)m * 512 + o] = acc[i][jj][r];
      }
    }
  }
}

// ---------------------------------------------------------------------------
// Attention (r5-proven version): one block per (b, h, 64-row strip),
// XCD-swizzled; P via wave-private LDS; bias as accumulator init.
// ---------------------------------------------------------------------------
__global__ __launch_bounds__(256) void attn_k(
    const bf16_t* __restrict__ qws, const bf16_t* __restrict__ kws,
    const bf16_t* __restrict__ vws, const float* __restrict__ biasws,
    bf16_t* __restrict__ aows) {
  __shared__ __align__(16) char smem[33792 + 16896];
  bf16_t* Ps = (bf16_t*)smem;            // 4 waves x [16][264]
  bf16_t* Vs = (bf16_t*)(smem + 33792);  // [32][264] transposed V

  const int id = blockIdx.x;             // 0..8191
  const int xcd = id & 7;
  const int jj = id >> 3;                // 0..1023
  const int bh = (jj >> 2) * 8 + xcd;    // 0..2047
  const int strip = jj & 3;
  const int h = bh & 15, b = bh >> 4;

  const int t = threadIdx.x;
  const int w = t >> 6, L = t & 63;
  const int lrow = L & 15, lq = L >> 4;

  const bf16_t* kbase = kws + (size_t)bh * 8192;
  const bf16_t* vbase = vws + (size_t)bh * 8192;
#pragma unroll
  for (int c = 0; c < 4; c++) {
    bf16x8 vv = *(const bf16x8*)(vbase + t * 32 + c * 8);
#pragma unroll
    for (int j = 0; j < 8; j++) Vs[(c * 8 + j) * 264 + t] = vv[j];
  }

  const bf16_t* qbase = qws + (size_t)bh * 8192 + (strip * 64 + w * 16) * 32;
  bf16x8 qf = *(const bf16x8*)(qbase + lrow * 32 + lq * 8);
  bf16x8 kf[16];
#pragma unroll
  for (int ct = 0; ct < 16; ct++)
    kf[ct] = *(const bf16x8*)(kbase + (ct * 16 + lrow) * 32 + lq * 8);

  const float* bb = biasws + h * 65536 + (strip * 4 + w) * 4096;
  f32x4 S[16];
#pragma unroll
  for (int ct = 0; ct < 16; ct++) {
    f32x4 bi = *(const f32x4*)(bb + ct * 256 + L * 4);
    S[ct] = MFMA_16x16x32(qf, kf[ct], bi);
  }

  float sm[4] = {0.f, 0.f, 0.f, 0.f};
#pragma unroll
  for (int ct = 0; ct < 16; ct++)
#pragma unroll
    for (int r = 0; r < 4; r++) {
      float e = __expf(S[ct][r]);
      S[ct][r] = e;
      sm[r] += e;
    }
#pragma unroll
  for (int r = 0; r < 4; r++)
#pragma unroll
    for (int msk = 1; msk < 16; msk <<= 1)
      sm[r] += __shfl_xor(sm[r], msk, 64);
  float inv[4];
#pragma unroll
  for (int r = 0; r < 4; r++) inv[r] = 1.0f / sm[r];

  bf16_t* Pw = Ps + w * 4224;
#pragma unroll
  for (int ct = 0; ct < 16; ct++)
#pragma unroll
    for (int r = 0; r < 4; r++)
      Pw[(lq * 4 + r) * 264 + ct * 16 + lrow] = (bf16_t)S[ct][r];

  __syncthreads();  // Vs writes visible to all waves

  f32x4 O0 = {}, O1 = {};
#pragma unroll
  for (int c = 0; c < 8; c++) {
    bf16x8 pf = *(const bf16x8*)&Pw[lrow * 264 + c * 32 + lq * 8];
    bf16x8 v0 = *(const bf16x8*)&Vs[lrow * 264 + c * 32 + lq * 8];
    bf16x8 v1 = *(const bf16x8*)&Vs[(16 + lrow) * 264 + c * 32 + lq * 8];
    O0 = MFMA_16x16x32(pf, v0, O0);
    O1 = MFMA_16x16x32(pf, v1, O1);
  }
  bf16_t* obase = aows + (size_t)(b * 256 + strip * 64 + w * 16) * 512 + h * 32;
#pragma unroll
  for (int r = 0; r < 4; r++) {
    int rl = lq * 4 + r;
    obase[rl * 512 + lrow] = (bf16_t)(O0[r] * inv[r]);
    obase[rl * 512 + 16 + lrow] = (bf16_t)(O1[r] * inv[r]);
  }
}

// ---------------------------------------------------------------------------
extern "C" void kernel_launch(void* const* d_in, const int* in_sizes, int n_in,
                              void* d_out, int out_size, void* d_ws, size_t ws_size,
                              hipStream_t stream) {
  (void)in_sizes; (void)n_in; (void)out_size; (void)ws_size;
  const float* x      = (const float*)d_in[0];
  const float* qkv_w  = (const float*)d_in[1];
  const float* qkv_b  = (const float*)d_in[2];
  const float* proj_w = (const float*)d_in[3];
  const float* proj_b = (const float*)d_in[4];
  const float* table  = (const float*)d_in[5];
  const int*   rel    = (const int*)d_in[6];

  const size_t QKV_ELEMS = 16777216;  // 128*16*256*32
  bf16_t* qws     = (bf16_t*)d_ws;
  bf16_t* kws     = qws + QKV_ELEMS;
  bf16_t* vws     = kws + QKV_ELEMS;
  float*  biasws  = (float*)(vws + QKV_ELEMS);
  bf16_t* wqkvbf  = (bf16_t*)(biasws + 1048576);
  bf16_t* wprojbf = wqkvbf + 786432;
  bf16_t* xbf     = wprojbf + 262144;  // aliased with aows (liveness disjoint)
  bf16_t* aows    = xbf;
  float*  out     = (float*)d_out;

  prep_k<<<12800, 256, 0, stream>>>(x, qkv_w, proj_w, table, rel,
                                    xbf, wqkvbf, wprojbf, biasws);
  qkv_gemm128_k<<<3072, 256, 0, stream>>>(xbf, wqkvbf, qkv_b, qws, kws, vws);
  attn_k<<<8192, 256, 0, stream>>>(qws, kws, vws, biasws, aows);
  proj_gemm128_k<<<1024, 256, 0, stream>>>(aows, wprojbf, proj_b, out);
}